// Round 1
// baseline (32.056 us; speedup 1.0000x reference)
//
#include <hip/hip_runtime.h>

// UpsampleFlow2: Gaussian Nadaraya-Watson upsampling.
// xyz [B,3,N] f32, sparse_xyz [B,3,S] f32, sparse_flow [B,3,S] f32, resol int.
// out [B,3,N] f32 = (sum_s k*f) / (sum_s k), k = exp(-|x-y|^2/r^2).
// Trick: exp(-x^2/r^2) cancels in num/den -> k' = exp2(c2*dot + y2c),
//   c2 = 2*log2e/r^2, y2c = -log2e*|y|^2/r^2 (precomputed into LDS).

constexpr int B_ = 4, N_ = 8192, S_ = 2048;
constexpr int BLOCK = 256, PPT = 4;
constexpr int PTS_PER_BLOCK = BLOCK * PPT;      // 1024
constexpr int NB = (B_ * N_) / PTS_PER_BLOCK;   // 32 n-blocks (8 per batch)
constexpr int BN = B_ * N_;                     // 32768
constexpr float LOG2E = 1.4426950408889634f;

template <int CHUNK>
__global__ __launch_bounds__(BLOCK, 2) void uf2_partial(
    const float* __restrict__ xyz,
    const float* __restrict__ sxyz,
    const float* __restrict__ sflow,
    const int* __restrict__ resol,
    float4* __restrict__ part)
{
    __shared__ float4 As[CHUNK];   // (yx, yy, yz, -log2e*|y|^2/r^2)
    __shared__ float4 Fs[CHUNK];   // (fx, fy, fz, 0)

    const int nb = blockIdx.x % NB;
    const int sc = blockIdx.x / NB;
    const int b  = nb >> 3;
    const int n0 = (nb & 7) * PTS_PER_BLOCK;
    const int s0 = sc * CHUNK;

    const float r      = (float)resol[0];       // INITIAL_RADIUS (=1) * resol
    const float inv_r2 = 1.0f / (r * r);
    const float c2 = 2.0f * inv_r2 * LOG2E;
    const float cy = -inv_r2 * LOG2E;

    // ---- stage sparse chunk into LDS (coalesced) ----
    const float* ybase = sxyz  + b * 3 * S_;
    const float* fbase = sflow + b * 3 * S_;
    for (int t = threadIdx.x; t < CHUNK; t += BLOCK) {
        const int s = s0 + t;
        const float yx = ybase[s], yy = ybase[S_ + s], yz = ybase[2 * S_ + s];
        const float fx = fbase[s], fy = fbase[S_ + s], fz = fbase[2 * S_ + s];
        As[t] = make_float4(yx, yy, yz, cy * (yx * yx + yy * yy + yz * yz));
        Fs[t] = make_float4(fx, fy, fz, 0.0f);
    }
    __syncthreads();

    // ---- per-thread query points ----
    const float* xbase = xyz + b * 3 * N_;
    float px[PPT], py[PPT], pz[PPT];
    float4 acc[PPT];
#pragma unroll
    for (int p = 0; p < PPT; ++p) {
        const int n = n0 + threadIdx.x + p * BLOCK;
        px[p] = xbase[n];
        py[p] = xbase[N_ + n];
        pz[p] = xbase[2 * N_ + n];
        acc[p] = make_float4(0.f, 0.f, 0.f, 0.f);
    }

    // ---- main loop over sparse chunk ----
#pragma unroll 4
    for (int t = 0; t < CHUNK; ++t) {
        const float4 a = As[t];   // broadcast ds_read_b128
        const float4 f = Fs[t];
#pragma unroll
        for (int p = 0; p < PPT; ++p) {
            float dot = px[p] * a.x;
            dot = fmaf(py[p], a.y, dot);
            dot = fmaf(pz[p], a.z, dot);
            const float k = __builtin_amdgcn_exp2f(fmaf(dot, c2, a.w));
            acc[p].x = fmaf(k, f.x, acc[p].x);
            acc[p].y = fmaf(k, f.y, acc[p].y);
            acc[p].z = fmaf(k, f.z, acc[p].z);
            acc[p].w += k;
        }
    }

    // ---- write partials (coalesced float4) ----
#pragma unroll
    for (int p = 0; p < PPT; ++p) {
        const int g = b * N_ + n0 + threadIdx.x + p * BLOCK;
        part[(size_t)sc * BN + g] = acc[p];
    }
}

__global__ __launch_bounds__(256) void uf2_combine(
    const float4* __restrict__ part, float* __restrict__ out, int SC)
{
    const int g = blockIdx.x * 256 + threadIdx.x;   // 0..BN-1
    float4 s = make_float4(0.f, 0.f, 0.f, 0.f);
    for (int c = 0; c < SC; ++c) {
        const float4 p = part[(size_t)c * BN + g];
        s.x += p.x; s.y += p.y; s.z += p.z; s.w += p.w;
    }
    const float inv = 1.0f / s.w;
    const int b = g >> 13;            // /8192
    const int n = g & (N_ - 1);
    float* ob = out + b * 3 * N_;
    ob[n]          = s.x * inv;
    ob[N_ + n]     = s.y * inv;
    ob[2 * N_ + n] = s.z * inv;
}

// Fallback if workspace is too small for even one partial chunk:
// single kernel, full S staged in LDS (64 KB), writes out directly.
__global__ __launch_bounds__(BLOCK, 1) void uf2_fused(
    const float* __restrict__ xyz,
    const float* __restrict__ sxyz,
    const float* __restrict__ sflow,
    const int* __restrict__ resol,
    float* __restrict__ out)
{
    __shared__ float4 As[S_];
    __shared__ float4 Fs[S_];

    const int nb = blockIdx.x;
    const int b  = nb >> 3;
    const int n0 = (nb & 7) * PTS_PER_BLOCK;

    const float r      = (float)resol[0];
    const float inv_r2 = 1.0f / (r * r);
    const float c2 = 2.0f * inv_r2 * LOG2E;
    const float cy = -inv_r2 * LOG2E;

    const float* ybase = sxyz  + b * 3 * S_;
    const float* fbase = sflow + b * 3 * S_;
    for (int t = threadIdx.x; t < S_; t += BLOCK) {
        const float yx = ybase[t], yy = ybase[S_ + t], yz = ybase[2 * S_ + t];
        const float fx = fbase[t], fy = fbase[S_ + t], fz = fbase[2 * S_ + t];
        As[t] = make_float4(yx, yy, yz, cy * (yx * yx + yy * yy + yz * yz));
        Fs[t] = make_float4(fx, fy, fz, 0.0f);
    }
    __syncthreads();

    const float* xbase = xyz + b * 3 * N_;
    float px[PPT], py[PPT], pz[PPT];
    float4 acc[PPT];
#pragma unroll
    for (int p = 0; p < PPT; ++p) {
        const int n = n0 + threadIdx.x + p * BLOCK;
        px[p] = xbase[n];
        py[p] = xbase[N_ + n];
        pz[p] = xbase[2 * N_ + n];
        acc[p] = make_float4(0.f, 0.f, 0.f, 0.f);
    }

#pragma unroll 4
    for (int t = 0; t < S_; ++t) {
        const float4 a = As[t];
        const float4 f = Fs[t];
#pragma unroll
        for (int p = 0; p < PPT; ++p) {
            float dot = px[p] * a.x;
            dot = fmaf(py[p], a.y, dot);
            dot = fmaf(pz[p], a.z, dot);
            const float k = __builtin_amdgcn_exp2f(fmaf(dot, c2, a.w));
            acc[p].x = fmaf(k, f.x, acc[p].x);
            acc[p].y = fmaf(k, f.y, acc[p].y);
            acc[p].z = fmaf(k, f.z, acc[p].z);
            acc[p].w += k;
        }
    }

#pragma unroll
    for (int p = 0; p < PPT; ++p) {
        const int n = n0 + threadIdx.x + p * BLOCK;
        const float inv = 1.0f / acc[p].w;
        float* ob = out + b * 3 * N_;
        ob[n]          = acc[p].x * inv;
        ob[N_ + n]     = acc[p].y * inv;
        ob[2 * N_ + n] = acc[p].z * inv;
    }
}

extern "C" void kernel_launch(void* const* d_in, const int* in_sizes, int n_in,
                              void* d_out, int out_size, void* d_ws, size_t ws_size,
                              hipStream_t stream)
{
    const float* xyz   = (const float*)d_in[0];
    const float* sxyz  = (const float*)d_in[1];
    const float* sflow = (const float*)d_in[2];
    const int*   resol = (const int*)d_in[3];
    float* out   = (float*)d_out;
    float4* part = (float4*)d_ws;

    const size_t per_chunk = (size_t)BN * sizeof(float4);   // 512 KB
    int SC = 16;
    while (SC > 1 && (size_t)SC * per_chunk > ws_size) SC >>= 1;

    if ((size_t)SC * per_chunk > ws_size) {
        // workspace too small even for SC=1 -> fused fallback (slower, correct)
        uf2_fused<<<dim3(NB), dim3(BLOCK), 0, stream>>>(xyz, sxyz, sflow, resol, out);
        return;
    }

    dim3 grid(NB * SC), blk(BLOCK);
    switch (SC) {
        case 16: uf2_partial<S_ / 16><<<grid, blk, 0, stream>>>(xyz, sxyz, sflow, resol, part); break;
        case 8:  uf2_partial<S_ / 8 ><<<grid, blk, 0, stream>>>(xyz, sxyz, sflow, resol, part); break;
        case 4:  uf2_partial<S_ / 4 ><<<grid, blk, 0, stream>>>(xyz, sxyz, sflow, resol, part); break;
        case 2:  uf2_partial<S_ / 2 ><<<grid, blk, 0, stream>>>(xyz, sxyz, sflow, resol, part); break;
        default: uf2_partial<S_     ><<<grid, blk, 0, stream>>>(xyz, sxyz, sflow, resol, part); break;
    }
    uf2_combine<<<dim3(BN / 256), dim3(256), 0, stream>>>(part, out, SC);
}